// Round 13
// baseline (5387.710 us; speedup 1.0000x reference)
//
#include <hip/hip_runtime.h>

// ---------------------------------------------------------------------------
// RNN seq2seq (2-layer Elman, enc 512 + dec 512, B=128, H=D=1024) + linear +
// log_softmax.
//
//   cvt kernels: weights f32 -> f16 (tiny, once per use)
//   gemm_bias: pre0_enc = X@Wih0_e^T + b          (f16 B operand)
//   rnn_phase (persistent, 256 WG): split-flag skewed pipeline
//   gemm_bias: pre0_dec from [X[512], Y[0..510]]
//   rnn_phase decoder, writes tops (f16)
//   gemm_bias: logits = tops@lin_W^T + lin_b  (f32 -> d_out)
//   logsoftmax_rows in-place on d_out
//
// Round-13 rnn_phase: SPLIT-FLAG decoupling of the two recurrence chains.
//  r12 proved store scope doesn't matter; the remaining serialization is the
//  single flag waiting for h0 + h1 + tops + full-block ack. New ordering
//  (memory semantics IDENTICAL to the proven r8-r12 protocol):
//   - flags0[b]=s+1  <=>  block b's h0[s] stores visible (published by
//     waves 0-1 right after their own wave-level vmcnt + LDS handshake)
//   - flags1[b]=s+1  <=>  block b's h1[s-1] stores visible (published by
//     waves 2-3 concurrently; tops store drains with vmcnt(1), off-path)
//   - consumers gate A-loads on flags0 and C-loads on flags1 (polled after
//     the h0 MFMAs -> h1 producers get that time for free)
//  Chains now overlap: step period ~ max(h0 chain, h1 chain), not sum.
//  Skew still <=2 steps (both polls gate the loop) << ring 16; all stores
//  write-through -> buffer_inv-every-8 remains safe.
// ---------------------------------------------------------------------------

typedef _Float16 f16;
typedef _Float16 f16x8 __attribute__((ext_vector_type(8)));
typedef _Float16 f16x4 __attribute__((ext_vector_type(4)));
typedef float    f32x4 __attribute__((ext_vector_type(4)));
typedef unsigned long long u64;

#define MFMA16(a, b, c) __builtin_amdgcn_mfma_f32_16x16x32_f16((a), (b), (c), 0, 0, 0)

__device__ __forceinline__ f32x4 zero4() {
  f32x4 v; v[0] = 0.f; v[1] = 0.f; v[2] = 0.f; v[3] = 0.f; return v;
}

__device__ __forceinline__ f16x8 cvt8(const float* __restrict__ p) {
  float4 a = *(const float4*)p;
  float4 b = *(const float4*)(p + 4);
  f16x8 r;
  r[0] = (f16)a.x; r[1] = (f16)a.y; r[2] = (f16)a.z; r[3] = (f16)a.w;
  r[4] = (f16)b.x; r[5] = (f16)b.y; r[6] = (f16)b.z; r[7] = (f16)b.w;
  return r;
}

__device__ __forceinline__ float fast_tanh(float x) {
  float e = __expf(2.f * x);
  return 1.f - 2.f / (e + 1.f);
}

// 8B agent write-through store (proven protocol store)
__device__ __forceinline__ void st8_ag(f16* p, f16x4 v) {
  asm volatile("global_store_dwordx2 %0, %1, off sc1" :: "v"(p), "v"(v) : "memory");
}
// self-waiting 8B load (L1-bypass); output valid at asm end
__device__ __forceinline__ f16x4 ld8_sync(const f16* p) {
  f16x4 r;
  asm volatile("global_load_dwordx2 %0, %1, off sc0\n\ts_waitcnt vmcnt(0)"
               : "=&v"(r) : "v"(p) : "memory");
  return r;
}

// 8 x dwordx4 from base (+64B steps) with wait INSIDE the block.
#define WLOAD8(dst, base)                                                     \
  asm volatile(                                                               \
      "global_load_dwordx4 %0, %8, off\n\t"                                   \
      "global_load_dwordx4 %1, %8, off offset:64\n\t"                         \
      "global_load_dwordx4 %2, %8, off offset:128\n\t"                        \
      "global_load_dwordx4 %3, %8, off offset:192\n\t"                        \
      "global_load_dwordx4 %4, %8, off offset:256\n\t"                        \
      "global_load_dwordx4 %5, %8, off offset:320\n\t"                        \
      "global_load_dwordx4 %6, %8, off offset:384\n\t"                        \
      "global_load_dwordx4 %7, %8, off offset:448\n\t"                        \
      "s_waitcnt vmcnt(0)"                                                    \
      : "=&v"(dst[0]), "=&v"(dst[1]), "=&v"(dst[2]), "=&v"(dst[3]),           \
        "=&v"(dst[4]), "=&v"(dst[5]), "=&v"(dst[6]), "=&v"(dst[7])            \
      : "v"(base) : "memory")

// ---------------------------------------------------------------------------
// GEMM: out[m][n] = sum_k A[m][k] * B[n][k] + bias1[n] (+ bias2[n])
// B is f16 when BF16 (pre-converted weights), else f32.
// ---------------------------------------------------------------------------
template <typename AT, bool BF16, bool OUT_F16>
__global__ __launch_bounds__(256)
void gemm_bias(const AT* __restrict__ A1, const AT* __restrict__ A2, int rowSplit,
               const void* __restrict__ B, const float* __restrict__ bias1,
               const float* __restrict__ bias2, void* __restrict__ outp,
               int M, int N, int K)
{
  __shared__ f16 Ash[128 * 64];
  __shared__ f16 Bsh[128 * 64];
  const int t = threadIdx.x;
  const int w = t >> 6, l = t & 63;
  const int wm = w >> 1, wn = w & 1;
  const int lrow = l & 15, lk8 = (l >> 4) * 8;
  const int m0 = blockIdx.y * 128, n0 = blockIdx.x * 128;
  const int sr = t >> 3;
  const int skf = (t & 7) * 8;

  f32x4 acc[4][4];
#pragma unroll
  for (int i = 0; i < 4; ++i)
#pragma unroll
    for (int j = 0; j < 4; ++j) acc[i][j] = zero4();

  f16x8 ar[4], br[4];

  auto loadA = [&](int r, int k) -> f16x8 {
    const int row = m0 + r;
    if constexpr (sizeof(AT) == 4) {
      const float* src = (row < rowSplit) ? ((const float*)A1 + (size_t)row * K)
                                          : ((const float*)A2 + (size_t)(row - rowSplit) * K);
      return cvt8(src + k);
    } else {
      const f16* src = (row < rowSplit) ? ((const f16*)A1 + (size_t)row * K)
                                        : ((const f16*)A2 + (size_t)(row - rowSplit) * K);
      return *(const f16x8*)(src + k);
    }
  };
  auto loadB = [&](int r, int k) -> f16x8 {
    if constexpr (BF16) return *(const f16x8*)((const f16*)B + (size_t)(n0 + r) * K + k);
    else                return cvt8((const float*)B + (size_t)(n0 + r) * K + k);
  };

#pragma unroll
  for (int s = 0; s < 4; ++s) { ar[s] = loadA(s * 32 + sr, skf); br[s] = loadB(s * 32 + sr, skf); }

  const int nkt = K >> 6;
  for (int kt = 0; kt < nkt; ++kt) {
#pragma unroll
    for (int s = 0; s < 4; ++s) {
      const int r = s * 32 + sr;
      const int di = r * 64 + (skf ^ ((r & 7) << 3));
      *(f16x8*)(Ash + di) = ar[s];
      *(f16x8*)(Bsh + di) = br[s];
    }
    __syncthreads();
    if (kt + 1 < nkt) {
      const int k0 = (kt + 1) << 6;
#pragma unroll
      for (int s = 0; s < 4; ++s) { ar[s] = loadA(s * 32 + sr, k0 + skf); br[s] = loadB(s * 32 + sr, k0 + skf); }
    }
#pragma unroll
    for (int ks = 0; ks < 2; ++ks) {
      const int kb = ks * 32 + lk8;
      f16x8 af[4], bf[4];
#pragma unroll
      for (int mt = 0; mt < 4; ++mt) {
        const int r = wm * 64 + mt * 16 + lrow;
        af[mt] = *(const f16x8*)(Ash + r * 64 + (kb ^ ((r & 7) << 3)));
      }
#pragma unroll
      for (int nt = 0; nt < 4; ++nt) {
        const int r = wn * 64 + nt * 16 + lrow;
        bf[nt] = *(const f16x8*)(Bsh + r * 64 + (kb ^ ((r & 7) << 3)));
      }
#pragma unroll
      for (int mt = 0; mt < 4; ++mt)
#pragma unroll
        for (int nt = 0; nt < 4; ++nt)
          acc[mt][nt] = MFMA16(af[mt], bf[nt], acc[mt][nt]);
    }
    __syncthreads();
  }

#pragma unroll
  for (int nt = 0; nt < 4; ++nt) {
    const int col = n0 + wn * 64 + nt * 16 + lrow;
    const float bv = bias1[col] + (bias2 ? bias2[col] : 0.f);
#pragma unroll
    for (int mt = 0; mt < 4; ++mt) {
#pragma unroll
      for (int r = 0; r < 4; ++r) {
        const int row = m0 + wm * 64 + mt * 16 + (l >> 4) * 4 + r;
        const float v = acc[mt][nt][r] + bv;
        if constexpr (OUT_F16) ((f16*)outp)[(size_t)row * N + col] = (f16)v;
        else                   ((float*)outp)[(size_t)row * N + col] = v;
      }
    }
  }
}

// ---------------------------------------------------------------------------
// Weight pre-convert kernels: f32 -> f16, 1024x1024 matrices.
// ---------------------------------------------------------------------------
__global__ __launch_bounds__(256)
void cvt_w3(const float* __restrict__ s0, const float* __restrict__ s1,
            const float* __restrict__ s2, f16* __restrict__ dst)
{
  const float* s = (blockIdx.y == 0) ? s0 : (blockIdx.y == 1) ? s1 : s2;
  const size_t base = (size_t)blockIdx.y << 20;
  const int i = (blockIdx.x * 256 + threadIdx.x) * 4;
  float4 v = *(const float4*)(s + i);
  f16x4 o;
  o[0] = (f16)v.x; o[1] = (f16)v.y; o[2] = (f16)v.z; o[3] = (f16)v.w;
  *(f16x4*)(dst + base + i) = o;
}

__global__ __launch_bounds__(256)
void cvt_w1(const float* __restrict__ s, f16* __restrict__ dst)
{
  const int i = (blockIdx.x * 256 + threadIdx.x) * 4;
  float4 v = *(const float4*)(s + i);
  f16x4 o;
  o[0] = (f16)v.x; o[1] = (f16)v.y; o[2] = (f16)v.z; o[3] = (f16)v.w;
  *(f16x4*)(dst + i) = o;
}

// ---------------------------------------------------------------------------
// Persistent RNN phase. 256 blocks x 256 threads, 1 block/CU.
// Block bid: group g = bid&7 (batch rows g*16..+15), slice = bid>>3 (out cols
// [slice*32,+32)). Wave w owns K-quarter kw=w*256 -> consumes the h columns
// produced by slice-blocks w*8..w*8+7 of its group (octet polls).
// Step s: h0[s] = tanh(pre0[s] + h0[s-1]@Whh0^T),
//         h1[s-1] = tanh(h0[s-1]@Wih1^T + h1[s-2]@Whh1^T + b1).
// h state: 16-deep rings [16][128][1024] f16.
//   At iter s: R0=(s+15)&15 W0=s&15 ; R1=(s+14)&15 W1=(s+15)&15.
// flags0 -> h0 visibility, flags1 -> h1 visibility (split publish).
// ---------------------------------------------------------------------------
__global__ __launch_bounds__(256, 1)
void rnn_phase(const f16* __restrict__ pre0,          // [512][128][1024]
               f16* __restrict__ h0b,                 // [16][128][1024]
               f16* __restrict__ h1b,                 // [16][128][1024]
               unsigned* sync,                        // flags0[256] | flags1[256]
               const f16* __restrict__ W0f, const f16* __restrict__ W1f,
               const f16* __restrict__ W2f,
               const float* __restrict__ bih1, const float* __restrict__ bhh1,
               f16* __restrict__ tops,                // [512][128][1024] or null
               int s_base)
{
  __shared__ float pbuf[8][16][36];      // [wave*2+part][row][col(pad 36)]
  __shared__ unsigned hs0, hs1;          // intra-block pair handshakes

  const int t = threadIdx.x;
  const int w = t >> 6, l = t & 63;
  const int lrow = l & 15, lk8 = (l >> 4) * 8;
  const int bid = blockIdx.x;
  const int g = bid & 7, slice = bid >> 3;
  const int rbase = g * 16, c0 = slice * 32;
  const bool is_dec = (s_base != 0);
  const int kw = w * 256;                // wave K-quarter (f16 elements)

  unsigned* flags0 = sync;               // [256]
  unsigned* flags1 = sync + 256;         // [256]

  if (t == 0) { hs0 = 0; hs1 = 0; }      // published by iter-0 __syncthreads

  // ---- weight slices -> VGPRs, self-waiting blocks (values valid now) ----
  f16x8 wv0[2][8], wv1[2][8], wv2[2][8];
#pragma unroll
  for (int ct = 0; ct < 2; ++ct) {
    const size_t wr = (size_t)(c0 + ct * 16 + lrow) * 1024 + kw + lk8;
    WLOAD8(wv0[ct], W0f + wr);
    WLOAD8(wv1[ct], W1f + wr);
    WLOAD8(wv2[ct], W2f + wr);
  }
  __builtin_amdgcn_sched_barrier(0);

  // epilogue mapping: 128 threads/part; thread -> (row, 4-col chunk)
  const int ep_p = t >> 7;             // 0: h0 (waves 0-1), 1: h1 (waves 2-3)
  const int sub = t & 127;
  const int ep_r = sub >> 3;           // 0..15
  const int ep_c = (sub & 7) * 4;      // 0..28
  float b1v[4];
#pragma unroll
  for (int i = 0; i < 4; ++i)
    b1v[i] = bih1[c0 + ep_c + i] + bhh1[c0 + ep_c + i];

  const int fidx = (g << 5) + slice;
  const f16* prep_base = pre0 + ((size_t)(rbase + ep_r)) * 1024 + c0 + ep_c;

  // per-wave producer octets (same offset into each flag array)
  const int octoff = (g << 5) + (w << 3) + (l & 7);
  unsigned* oct0 = flags0 + octoff;
  unsigned* oct1 = flags1 + octoff;

  // prologue: prefetch pre0 for s_loc = 0
  f16x4 pre_next;
#pragma unroll
  for (int i = 0; i < 4; ++i) pre_next[i] = (f16)0.f;
  if (ep_p == 0)
    pre_next = *(const f16x4*)prep_base;

  for (int s_loc = 0; s_loc <= 512; ++s_loc) {
    const int s = s_base + s_loc;
    const f16x4 pre4 = pre_next;       // prefetched last iteration

    // periodic own-L2 invalidate (proven): bounds sc0 staleness to 8 steps
    // (< ring distance 16); s_loc==0 also clears cross-phase/replay lines.
    if ((s_loc & 7) == 0) {
      if (t == 0)
        asm volatile("buffer_inv\n\ts_waitcnt vmcnt(0)" ::: "memory");
      __syncthreads();
    }

    const int R0 = (s + 15) & 15, Wr0 = s & 15;
    const int R1 = (s + 14) & 15, Wr1 = (s + 15) & 15;
    const f16* h0p = h0b + (size_t)R0 * 131072;
    const f16* h1p = h1b + (size_t)R1 * 131072;
    f16* h0w = h0b + (size_t)Wr0 * 131072;
    f16* h1w = h1b + (size_t)Wr1 * 131072;
    const bool cmp_h0 = (s_loc < 512);
    const bool h1_copy = (is_dec && s_loc == 0);
    const bool cmp_h1 = !((!is_dec && s_loc == 0) || h1_copy);

    // ---- pollH0: wave w waits for ITS 8 h0 producers of step s_loc-1 ----
    if (s_loc > 0) {
      const unsigned tgt = (unsigned)s_loc;
      int it = 0;
      for (;;) {
        unsigned v;
        if (((++it) & 7) == 0) {
          v = __hip_atomic_load(oct0, __ATOMIC_RELAXED, __HIP_MEMORY_SCOPE_AGENT);
          if (__all((l < 8) ? (int)(v >= tgt) : 1)) break;
          __builtin_amdgcn_s_sleep(1);
        } else {
          asm volatile("global_load_dword %0, %1, off sc0\n\ts_waitcnt vmcnt(0)"
                       : "=&v"(v) : "v"(oct0) : "memory");
          if (__all((l < 8) ? (int)(v >= tgt) : 1)) break;
        }
      }
    }

    // ---- A loads (h0_prev), self-waiting ----
    f16x8 A[8];
    const f16* ap = h0p + (size_t)(rbase + lrow) * 1024 + kw + lk8;
    WLOAD8(A, ap);
    __builtin_amdgcn_sched_barrier(0);

    f32x4 acc0[2], acc1[2];
    acc0[0] = zero4(); acc0[1] = zero4(); acc1[0] = zero4(); acc1[1] = zero4();

    // h0 chain MFMAs + the A-half of h1
#pragma unroll
    for (int j = 0; j < 8; ++j) {
#pragma unroll
      for (int ct = 0; ct < 2; ++ct) {
        acc0[ct] = MFMA16(A[j], wv0[ct][j], acc0[ct]);
        acc1[ct] = MFMA16(A[j], wv1[ct][j], acc1[ct]);
      }
    }

    // ---- pollH1 (after h0 MFMAs: h1 producers get that time free) ----
    if (s_loc > 0) {
      const unsigned tgt = (unsigned)s_loc;
      int it = 0;
      for (;;) {
        unsigned v;
        if (((++it) & 7) == 0) {
          v = __hip_atomic_load(oct1, __ATOMIC_RELAXED, __HIP_MEMORY_SCOPE_AGENT);
          if (__all((l < 8) ? (int)(v >= tgt) : 1)) break;
          __builtin_amdgcn_s_sleep(1);
        } else {
          asm volatile("global_load_dword %0, %1, off sc0\n\ts_waitcnt vmcnt(0)"
                       : "=&v"(v) : "v"(oct1) : "memory");
          if (__all((l < 8) ? (int)(v >= tgt) : 1)) break;
        }
      }
    }

    // ---- C loads (h1_prev2), self-waiting, then C-half of h1 ----
    f16x8 C[8];
    const f16* cp = h1p + (size_t)(rbase + lrow) * 1024 + kw + lk8;
    WLOAD8(C, cp);
    __builtin_amdgcn_sched_barrier(0);
#pragma unroll
    for (int j = 0; j < 8; ++j) {
#pragma unroll
      for (int ct = 0; ct < 2; ++ct)
        acc1[ct] = MFMA16(C[j], wv2[ct][j], acc1[ct]);
    }

    // partials -> LDS
#pragma unroll
    for (int ct = 0; ct < 2; ++ct)
#pragma unroll
      for (int r = 0; r < 4; ++r) {
        const int row = (l >> 4) * 4 + r;
        pbuf[w * 2 + 0][row][ct * 16 + lrow] = acc0[ct][r];
        pbuf[w * 2 + 1][row][ct * 16 + lrow] = acc1[ct][r];
      }
    __syncthreads();                    // b1: all partials in LDS

    // ---- parallel epilogues + split publish ----
    if (ep_p == 0) {
      // h0 epilogue (waves 0-1)
      if (cmp_h0) {
        f32x4 sa = zero4();
#pragma unroll
        for (int ww = 0; ww < 4; ++ww)
          sa += *(const f32x4*)&pbuf[ww * 2 + 0][ep_r][ep_c];
        f16x4 o;
#pragma unroll
        for (int i = 0; i < 4; ++i) o[i] = (f16)fast_tanh(sa[i] + (float)pre4[i]);
        st8_ag(h0w + (size_t)(rbase + ep_r) * 1024 + c0 + ep_c, o);
      } else {                          // drain step: carry h0[511] forward
        f16x4 v = ld8_sync(h0p + (size_t)(rbase + ep_r) * 1024 + c0 + ep_c);
        st8_ag(h0w + (size_t)(rbase + ep_r) * 1024 + c0 + ep_c, v);
      }
      asm volatile("s_waitcnt vmcnt(0)" ::: "memory");  // wave-level h0 ack
      if (w == 1) {
        if (l == 0)
          __hip_atomic_store(&hs0, (unsigned)(s_loc + 1),
                             __ATOMIC_RELEASE, __HIP_MEMORY_SCOPE_WORKGROUP);
      } else {                          // wave 0: wait pair, publish flags0
        if (l == 0) {
          while (__hip_atomic_load(&hs0, __ATOMIC_ACQUIRE,
                                   __HIP_MEMORY_SCOPE_WORKGROUP) < (unsigned)(s_loc + 1)) {}
          if (s_loc < 512) {
            const unsigned val = (unsigned)(s_loc + 1);
            asm volatile("global_store_dword %0, %1, off sc0 sc1"
                         :: "v"(flags0 + fidx), "v"(val) : "memory");
          }
        }
      }
      // prefetch next step's pre0 (hides under b2 + next head polls)
      if (s_loc < 511)
        pre_next = *(const f16x4*)(prep_base + (size_t)(s_loc + 1) * 131072);
    } else {
      // h1 epilogue (waves 2-3)
      if (cmp_h1) {
        f32x4 sa = zero4();
#pragma unroll
        for (int ww = 0; ww < 4; ++ww)
          sa += *(const f32x4*)&pbuf[ww * 2 + 1][ep_r][ep_c];
        f16x4 o;
#pragma unroll
        for (int i = 0; i < 4; ++i) o[i] = (f16)fast_tanh(sa[i] + b1v[i]);
        st8_ag(h1w + (size_t)(rbase + ep_r) * 1024 + c0 + ep_c, o);
        if (tops && s_loc >= 1) {       // tops drains AFTER h1 (vmcnt(1))
          *(f16x4*)(tops + ((size_t)(s_loc - 1) * 128 + rbase + ep_r) * 1024 + c0 + ep_c) = o;
          asm volatile("s_waitcnt vmcnt(1)" ::: "memory");
        } else {
          asm volatile("s_waitcnt vmcnt(0)" ::: "memory");
        }
      } else if (h1_copy) {             // dec fill step: carry h1_enc[511]
        f16x4 v = ld8_sync(h1p + (size_t)(rbase + ep_r) * 1024 + c0 + ep_c);
        st8_ag(h1w + (size_t)(rbase + ep_r) * 1024 + c0 + ep_c, v);
        asm volatile("s_waitcnt vmcnt(0)" ::: "memory");
      } else {
        asm volatile("s_waitcnt vmcnt(0)" ::: "memory");
      }
      if (w == 3) {
        if (l == 0)
          __hip_atomic_store(&hs1, (unsigned)(s_loc + 1),
                             __ATOMIC_RELEASE, __HIP_MEMORY_SCOPE_WORKGROUP);
      } else {                          // wave 2: wait pair, publish flags1
        if (l == 0) {
          while (__hip_atomic_load(&hs1, __ATOMIC_ACQUIRE,
                                   __HIP_MEMORY_SCOPE_WORKGROUP) < (unsigned)(s_loc + 1)) {}
          if (s_loc < 512) {
            const unsigned val = (unsigned)(s_loc + 1);
            asm volatile("global_store_dword %0, %1, off sc0 sc1"
                         :: "v"(flags1 + fidx), "v"(val) : "memory");
          }
        }
      }
    }
    __syncthreads();                    // b2: pbuf safe for next iteration
  }
}

// ---------------------------------------------------------------------------
// In-place log_softmax over rows of 1024 f32.
// ---------------------------------------------------------------------------
__global__ __launch_bounds__(256)
void logsoftmax_rows(float* __restrict__ x)
{
  const int row = blockIdx.x;
  const int t = threadIdx.x;
  float* p = x + (size_t)row * 1024;
  float4 v = ((float4*)p)[t];
  float m = fmaxf(fmaxf(v.x, v.y), fmaxf(v.z, v.w));
#pragma unroll
  for (int off = 32; off >= 1; off >>= 1) m = fmaxf(m, __shfl_xor(m, off));
  __shared__ float red[4];
  __shared__ float red2[4];
  const int w = t >> 6;
  if ((t & 63) == 0) red[w] = m;
  __syncthreads();
  m = fmaxf(fmaxf(red[0], red[1]), fmaxf(red[2], red[3]));
  float s = __expf(v.x - m) + __expf(v.y - m) + __expf(v.z - m) + __expf(v.w - m);
#pragma unroll
  for (int off = 32; off >= 1; off >>= 1) s += __shfl_xor(s, off);
  if ((t & 63) == 0) red2[w] = s;
  __syncthreads();
  s = red2[0] + red2[1] + red2[2] + red2[3];
  const float lse = m + __logf(s);
  v.x -= lse; v.y -= lse; v.z -= lse; v.w -= lse;
  ((float4*)p)[t] = v;
}

// ---------------------------------------------------------------------------
extern "C" void kernel_launch(void* const* d_in, const int* in_sizes, int n_in,
                              void* d_out, int out_size, void* d_ws, size_t ws_size,
                              hipStream_t stream)
{
  (void)in_sizes; (void)n_in; (void)out_size; (void)ws_size;

  const float* X    = (const float*)d_in[0];   // [513][128][1024]
  const float* Y    = (const float*)d_in[1];   // [512][128][1024]
  const float* eWih = (const float*)d_in[2];   // [2][1024][1024]
  const float* eWhh = (const float*)d_in[3];
  const float* ebih = (const float*)d_in[4];   // [2][1024]
  const float* ebhh = (const float*)d_in[5];
  const float* dWih = (const float*)d_in[6];
  const float* dWhh = (const float*)d_in[7];
  const float* dbih = (const float*)d_in[8];
  const float* dbhh = (const float*)d_in[9];
  const float* linW = (const float*)d_in[10];  // [1024][1024]
  const float* linb = (const float*)d_in[11];  // [1024]

  // workspace layout
  char* ws = (char*)d_ws;
  unsigned* sync = (unsigned*)ws;                                 // 2KB used
  f16* h0b  = (f16*)(ws + 65536);                                 // 16*256KB = 4MB
  f16* h1b  = (f16*)(ws + 65536 + (16u << 18));                   // 4MB
  f16* wcvt = (f16*)(ws + (9u << 20));                            // 6MB @ 9MB
  f16* pre0 = (f16*)(ws + (16u << 20));                           // 128MB @ 16MB
  f16* tops = (f16*)(ws + (144u << 20));                          // 128MB @ 144MB
  f16* tmpB = tops;                    // 2MB scratch; tops not live until dec rnn

  const size_t LAYER1 = 1024 * 1024;
  const size_t MEG = 1024 * 1024;
  const int M = 512 * 128;

  // zero flags + both h rings
  hipMemsetAsync(d_ws, 0, 65536 + (32u << 18), stream);

  dim3 ggrid(8, 512);
  dim3 cgrid3(1024, 3);

  // encoder input-GEMM B (Wih0_e) -> f16 scratch, then GEMM
  cvt_w1<<<1024, 256, 0, stream>>>(eWih, tmpB);
  gemm_bias<float, true, true><<<ggrid, 256, 0, stream>>>(
      X, X, 1 << 30, tmpB, ebih, ebhh, pre0, M, 1024, 1024);

  // encoder recurrent weights -> f16, then encoder recurrence
  cvt_w3<<<cgrid3, 256, 0, stream>>>(eWhh, eWih + LAYER1, eWhh + LAYER1, wcvt);
  rnn_phase<<<256, 256, 0, stream>>>(
      pre0, h0b, h1b, sync,
      wcvt, wcvt + MEG, wcvt + 2 * MEG, ebih + 1024, ebhh + 1024,
      nullptr, 0);

  // decoder input-GEMM B (Wih0_d) -> f16 scratch (enc GEMM done), then GEMM
  cvt_w1<<<1024, 256, 0, stream>>>(dWih, tmpB);
  gemm_bias<float, true, true><<<ggrid, 256, 0, stream>>>(
      X + (size_t)512 * 128 * 1024, Y, 128, tmpB, dbih, dbhh, pre0, M, 1024, 1024);

  // reset flags for decoder phase (hidden state carries over)
  hipMemsetAsync(d_ws, 0, 4096, stream);

  // decoder recurrent weights -> f16 (after enc rnn: buffer reuse), then rnn
  cvt_w3<<<cgrid3, 256, 0, stream>>>(dWhh, dWih + LAYER1, dWhh + LAYER1, wcvt);
  rnn_phase<<<256, 256, 0, stream>>>(
      pre0, h0b, h1b, sync,
      wcvt, wcvt + MEG, wcvt + 2 * MEG, dbih + 1024, dbhh + 1024,
      tops, 513);

  // final linear: linW -> f16 (wcvt free after dec rnn), logits -> d_out
  cvt_w1<<<1024, 256, 0, stream>>>(linW, wcvt);
  gemm_bias<f16, true, false><<<ggrid, 256, 0, stream>>>(
      tops, tops, 1 << 30, wcvt, linb, nullptr, d_out, M, 1024, 1024);

  // in-place log_softmax
  logsoftmax_rows<<<M, 256, 0, stream>>>((float*)d_out);
}

// Round 14
// 5020.500 us; speedup vs baseline: 1.0731x; 1.0731x over previous
//
#include <hip/hip_runtime.h>

// ---------------------------------------------------------------------------
// RNN seq2seq (2-layer Elman, enc 512 + dec 512, B=128, H=D=1024) + linear +
// log_softmax.
//
//   cvt kernels: weights f32 -> f16 (tiny, once per use)
//   gemm_bias: pre0_enc = X@Wih0_e^T + b          (f16 B operand)
//   rnn_phase (persistent, 256 WG): octet-gated skewed pipeline (r12, best)
//   gemm_bias: pre0_dec from [X[512], Y[0..510]]
//   rnn_phase decoder, writes tops (f16)
//   gemm_bias: logits(f16) = tops@lin_W^T + lin_b  -> scratch
//   logsoftmax_rows_h: f16 logits -> f32 log-softmax in d_out
//
// Round-14 (final): rnn_phase reverted byte-for-byte to r12 (best measured;
// r13's split-flag handshakes regressed). One new tail optimization: the
// final GEMM writes f16 logits (halves its store traffic) and logsoftmax
// reads f16 / writes f32 d_out — cuts the tail's HBM volume 681 -> 453 MB.
// Recurrence protocol (proven r8/r12): producer sc1 write-through stores
// (MALL = truth), consumer sc0 loads, buffer_inv every 8 steps (< ring
// reuse distance 16); per-wave octet head-poll of the 8 producers whose
// columns the wave consumes; flag stores sc0 sc1.
// ---------------------------------------------------------------------------

typedef _Float16 f16;
typedef _Float16 f16x8 __attribute__((ext_vector_type(8)));
typedef _Float16 f16x4 __attribute__((ext_vector_type(4)));
typedef float    f32x4 __attribute__((ext_vector_type(4)));
typedef unsigned long long u64;

#define MFMA16(a, b, c) __builtin_amdgcn_mfma_f32_16x16x32_f16((a), (b), (c), 0, 0, 0)

__device__ __forceinline__ f32x4 zero4() {
  f32x4 v; v[0] = 0.f; v[1] = 0.f; v[2] = 0.f; v[3] = 0.f; return v;
}

__device__ __forceinline__ f16x8 cvt8(const float* __restrict__ p) {
  float4 a = *(const float4*)p;
  float4 b = *(const float4*)(p + 4);
  f16x8 r;
  r[0] = (f16)a.x; r[1] = (f16)a.y; r[2] = (f16)a.z; r[3] = (f16)a.w;
  r[4] = (f16)b.x; r[5] = (f16)b.y; r[6] = (f16)b.z; r[7] = (f16)b.w;
  return r;
}

__device__ __forceinline__ float fast_tanh(float x) {
  float e = __expf(2.f * x);
  return 1.f - 2.f / (e + 1.f);
}

// 8B agent write-through store (proven protocol store)
__device__ __forceinline__ void st8_ag(f16* p, f16x4 v) {
  asm volatile("global_store_dwordx2 %0, %1, off sc1" :: "v"(p), "v"(v) : "memory");
}
// self-waiting 8B load (L1-bypass); output valid at asm end
__device__ __forceinline__ f16x4 ld8_sync(const f16* p) {
  f16x4 r;
  asm volatile("global_load_dwordx2 %0, %1, off sc0\n\ts_waitcnt vmcnt(0)"
               : "=&v"(r) : "v"(p) : "memory");
  return r;
}

// 8 x dwordx4 from base (+64B steps) with wait INSIDE the block.
#define WLOAD8(dst, base)                                                     \
  asm volatile(                                                               \
      "global_load_dwordx4 %0, %8, off\n\t"                                   \
      "global_load_dwordx4 %1, %8, off offset:64\n\t"                         \
      "global_load_dwordx4 %2, %8, off offset:128\n\t"                        \
      "global_load_dwordx4 %3, %8, off offset:192\n\t"                        \
      "global_load_dwordx4 %4, %8, off offset:256\n\t"                        \
      "global_load_dwordx4 %5, %8, off offset:320\n\t"                        \
      "global_load_dwordx4 %6, %8, off offset:384\n\t"                        \
      "global_load_dwordx4 %7, %8, off offset:448\n\t"                        \
      "s_waitcnt vmcnt(0)"                                                    \
      : "=&v"(dst[0]), "=&v"(dst[1]), "=&v"(dst[2]), "=&v"(dst[3]),           \
        "=&v"(dst[4]), "=&v"(dst[5]), "=&v"(dst[6]), "=&v"(dst[7])            \
      : "v"(base) : "memory")

// ---------------------------------------------------------------------------
// GEMM: out[m][n] = sum_k A[m][k] * B[n][k] + bias1[n] (+ bias2[n])
// B is f16 when BF16 (pre-converted weights), else f32.
// ---------------------------------------------------------------------------
template <typename AT, bool BF16, bool OUT_F16>
__global__ __launch_bounds__(256)
void gemm_bias(const AT* __restrict__ A1, const AT* __restrict__ A2, int rowSplit,
               const void* __restrict__ B, const float* __restrict__ bias1,
               const float* __restrict__ bias2, void* __restrict__ outp,
               int M, int N, int K)
{
  __shared__ f16 Ash[128 * 64];
  __shared__ f16 Bsh[128 * 64];
  const int t = threadIdx.x;
  const int w = t >> 6, l = t & 63;
  const int wm = w >> 1, wn = w & 1;
  const int lrow = l & 15, lk8 = (l >> 4) * 8;
  const int m0 = blockIdx.y * 128, n0 = blockIdx.x * 128;
  const int sr = t >> 3;
  const int skf = (t & 7) * 8;

  f32x4 acc[4][4];
#pragma unroll
  for (int i = 0; i < 4; ++i)
#pragma unroll
    for (int j = 0; j < 4; ++j) acc[i][j] = zero4();

  f16x8 ar[4], br[4];

  auto loadA = [&](int r, int k) -> f16x8 {
    const int row = m0 + r;
    if constexpr (sizeof(AT) == 4) {
      const float* src = (row < rowSplit) ? ((const float*)A1 + (size_t)row * K)
                                          : ((const float*)A2 + (size_t)(row - rowSplit) * K);
      return cvt8(src + k);
    } else {
      const f16* src = (row < rowSplit) ? ((const f16*)A1 + (size_t)row * K)
                                        : ((const f16*)A2 + (size_t)(row - rowSplit) * K);
      return *(const f16x8*)(src + k);
    }
  };
  auto loadB = [&](int r, int k) -> f16x8 {
    if constexpr (BF16) return *(const f16x8*)((const f16*)B + (size_t)(n0 + r) * K + k);
    else                return cvt8((const float*)B + (size_t)(n0 + r) * K + k);
  };

#pragma unroll
  for (int s = 0; s < 4; ++s) { ar[s] = loadA(s * 32 + sr, skf); br[s] = loadB(s * 32 + sr, skf); }

  const int nkt = K >> 6;
  for (int kt = 0; kt < nkt; ++kt) {
#pragma unroll
    for (int s = 0; s < 4; ++s) {
      const int r = s * 32 + sr;
      const int di = r * 64 + (skf ^ ((r & 7) << 3));
      *(f16x8*)(Ash + di) = ar[s];
      *(f16x8*)(Bsh + di) = br[s];
    }
    __syncthreads();
    if (kt + 1 < nkt) {
      const int k0 = (kt + 1) << 6;
#pragma unroll
      for (int s = 0; s < 4; ++s) { ar[s] = loadA(s * 32 + sr, k0 + skf); br[s] = loadB(s * 32 + sr, k0 + skf); }
    }
#pragma unroll
    for (int ks = 0; ks < 2; ++ks) {
      const int kb = ks * 32 + lk8;
      f16x8 af[4], bf[4];
#pragma unroll
      for (int mt = 0; mt < 4; ++mt) {
        const int r = wm * 64 + mt * 16 + lrow;
        af[mt] = *(const f16x8*)(Ash + r * 64 + (kb ^ ((r & 7) << 3)));
      }
#pragma unroll
      for (int nt = 0; nt < 4; ++nt) {
        const int r = wn * 64 + nt * 16 + lrow;
        bf[nt] = *(const f16x8*)(Bsh + r * 64 + (kb ^ ((r & 7) << 3)));
      }
#pragma unroll
      for (int mt = 0; mt < 4; ++mt)
#pragma unroll
        for (int nt = 0; nt < 4; ++nt)
          acc[mt][nt] = MFMA16(af[mt], bf[nt], acc[mt][nt]);
    }
    __syncthreads();
  }

#pragma unroll
  for (int nt = 0; nt < 4; ++nt) {
    const int col = n0 + wn * 64 + nt * 16 + lrow;
    const float bv = bias1[col] + (bias2 ? bias2[col] : 0.f);
#pragma unroll
    for (int mt = 0; mt < 4; ++mt) {
#pragma unroll
      for (int r = 0; r < 4; ++r) {
        const int row = m0 + wm * 64 + mt * 16 + (l >> 4) * 4 + r;
        const float v = acc[mt][nt][r] + bv;
        if constexpr (OUT_F16) ((f16*)outp)[(size_t)row * N + col] = (f16)v;
        else                   ((float*)outp)[(size_t)row * N + col] = v;
      }
    }
  }
}

// ---------------------------------------------------------------------------
// Weight pre-convert kernels: f32 -> f16, 1024x1024 matrices.
// ---------------------------------------------------------------------------
__global__ __launch_bounds__(256)
void cvt_w3(const float* __restrict__ s0, const float* __restrict__ s1,
            const float* __restrict__ s2, f16* __restrict__ dst)
{
  const float* s = (blockIdx.y == 0) ? s0 : (blockIdx.y == 1) ? s1 : s2;
  const size_t base = (size_t)blockIdx.y << 20;
  const int i = (blockIdx.x * 256 + threadIdx.x) * 4;
  float4 v = *(const float4*)(s + i);
  f16x4 o;
  o[0] = (f16)v.x; o[1] = (f16)v.y; o[2] = (f16)v.z; o[3] = (f16)v.w;
  *(f16x4*)(dst + base + i) = o;
}

__global__ __launch_bounds__(256)
void cvt_w1(const float* __restrict__ s, f16* __restrict__ dst)
{
  const int i = (blockIdx.x * 256 + threadIdx.x) * 4;
  float4 v = *(const float4*)(s + i);
  f16x4 o;
  o[0] = (f16)v.x; o[1] = (f16)v.y; o[2] = (f16)v.z; o[3] = (f16)v.w;
  *(f16x4*)(dst + i) = o;
}

// ---------------------------------------------------------------------------
// Persistent RNN phase (r12, best measured). 256 blocks x 256 threads.
// Block bid: group g = bid&7 (batch rows g*16..+15), slice = bid>>3 (out cols
// [slice*32,+32)). Wave w owns K-quarter kw=w*256 -> consumes h columns
// produced by slice-blocks w*8..w*8+7 of its group -> per-wave octet flag
// poll at loop head. Weight slices resident in 192 regs.
// Step s: h0[s] = tanh(pre0[s] + h0[s-1]@Whh0^T),
//         h1[s-1] = tanh(h0[s-1]@Wih1^T + h1[s-2]@Whh1^T + b1).
// h state: 16-deep rings [16][128][1024] f16.
//   At iter s: R0=(s+15)&15 W0=s&15 ; R1=(s+14)&15 W1=(s+15)&15.
// Max inter-block skew = 1 step -> ring safety unchanged.
// ---------------------------------------------------------------------------
__global__ __launch_bounds__(256, 1)
void rnn_phase(const f16* __restrict__ pre0,          // [512][128][1024]
               f16* __restrict__ h0b,                 // [16][128][1024]
               f16* __restrict__ h1b,                 // [16][128][1024]
               unsigned* flags,                       // [256] per-block step flags
               const f16* __restrict__ W0f, const f16* __restrict__ W1f,
               const f16* __restrict__ W2f,
               const float* __restrict__ bih1, const float* __restrict__ bhh1,
               f16* __restrict__ tops,                // [512][128][1024] or null
               int s_base)
{
  __shared__ float pbuf[8][16][36];      // [wave*2+part][row][col(pad 36)]

  const int t = threadIdx.x;
  const int w = t >> 6, l = t & 63;
  const int lrow = l & 15, lk8 = (l >> 4) * 8;
  const int bid = blockIdx.x;
  const int g = bid & 7, slice = bid >> 3;
  const int rbase = g * 16, c0 = slice * 32;
  const bool is_dec = (s_base != 0);
  const int kw = w * 256;                // wave K-quarter (f16 elements)

  // ---- weight slices -> VGPRs, self-waiting blocks (values valid now) ----
  f16x8 wv0[2][8], wv1[2][8], wv2[2][8];
#pragma unroll
  for (int ct = 0; ct < 2; ++ct) {
    const size_t wr = (size_t)(c0 + ct * 16 + lrow) * 1024 + kw + lk8;
    WLOAD8(wv0[ct], W0f + wr);
    WLOAD8(wv1[ct], W1f + wr);
    WLOAD8(wv2[ct], W2f + wr);
  }
  __builtin_amdgcn_sched_barrier(0);

  // epilogue mapping: 128 threads/part; thread -> (row, 4-col chunk)
  const int ep_p = t >> 7;             // 0: h0, 1: h1
  const int sub = t & 127;
  const int ep_r = sub >> 3;           // 0..15
  const int ep_c = (sub & 7) * 4;      // 0..28
  float b1v[4];
#pragma unroll
  for (int i = 0; i < 4; ++i)
    b1v[i] = bih1[c0 + ep_c + i] + bhh1[c0 + ep_c + i];

  const int fidx = (g << 5) + slice;
  const f16* prep_base = pre0 + ((size_t)(rbase + ep_r)) * 1024 + c0 + ep_c;

  // per-wave producer octet: flags of slice-blocks w*8 .. w*8+7 of my group
  unsigned* octet_fp = flags + (g << 5) + (w << 3) + (l & 7);

  // prologue: prefetch pre0 for s_loc = 0
  f16x4 pre_next;
#pragma unroll
  for (int i = 0; i < 4; ++i) pre_next[i] = (f16)0.f;
  if (ep_p == 0)
    pre_next = *(const f16x4*)prep_base;

  for (int s_loc = 0; s_loc <= 512; ++s_loc) {
    const int s = s_base + s_loc;
    const f16x4 pre4 = pre_next;       // prefetched last iteration

    // periodic own-L2 invalidate: bounds sc0 staleness to 8 steps (< ring
    // reuse distance 16); s_loc==0 also clears cross-phase/replay lines.
    // Safe: all inter-block stores are write-through (no dirty L2 lines).
    if ((s_loc & 7) == 0) {
      if (t == 0)
        asm volatile("buffer_inv\n\ts_waitcnt vmcnt(0)" ::: "memory");
      __syncthreads();
    }

    // ---- HEAD poll: wave w waits only for ITS 8 producers ----
    if (s_loc > 0) {
      const unsigned tgt = (unsigned)s_loc;
      int it = 0;
      for (;;) {
        unsigned v;
        if (((++it) & 7) == 0) {       // MALL-fresh: guarantees progress
          v = __hip_atomic_load(octet_fp, __ATOMIC_RELAXED, __HIP_MEMORY_SCOPE_AGENT);
          if (__all((l < 8) ? (int)(v >= tgt) : 1)) break;
          __builtin_amdgcn_s_sleep(1);
        } else {
          asm volatile("global_load_dword %0, %1, off sc0\n\ts_waitcnt vmcnt(0)"
                       : "=&v"(v) : "v"(octet_fp) : "memory");
          if (__all((l < 8) ? (int)(v >= tgt) : 1)) break;
        }
      }
    }

    const int R0 = (s + 15) & 15, Wr0 = s & 15;
    const int R1 = (s + 14) & 15, Wr1 = (s + 15) & 15;
    const f16* h0p = h0b + (size_t)R0 * 131072;
    const f16* h1p = h1b + (size_t)R1 * 131072;
    f16* h0w = h0b + (size_t)Wr0 * 131072;
    f16* h1w = h1b + (size_t)Wr1 * 131072;
    const bool cmp_h0 = (s_loc < 512);
    const bool h1_copy = (is_dec && s_loc == 0);
    const bool cmp_h1 = !((!is_dec && s_loc == 0) || h1_copy);

    // ---- all 16 h-state loads in ONE self-waiting asm block (sc0) ----
    f16x8 A[8], C[8];
    const f16* ap = h0p + (size_t)(rbase + lrow) * 1024 + kw + lk8;
    const f16* cp = h1p + (size_t)(rbase + lrow) * 1024 + kw + lk8;
    asm volatile(
        "global_load_dwordx4 %0, %16, off sc0\n\t"
        "global_load_dwordx4 %1, %16, off offset:64 sc0\n\t"
        "global_load_dwordx4 %2, %16, off offset:128 sc0\n\t"
        "global_load_dwordx4 %3, %16, off offset:192 sc0\n\t"
        "global_load_dwordx4 %4, %16, off offset:256 sc0\n\t"
        "global_load_dwordx4 %5, %16, off offset:320 sc0\n\t"
        "global_load_dwordx4 %6, %16, off offset:384 sc0\n\t"
        "global_load_dwordx4 %7, %16, off offset:448 sc0\n\t"
        "global_load_dwordx4 %8, %17, off sc0\n\t"
        "global_load_dwordx4 %9, %17, off offset:64 sc0\n\t"
        "global_load_dwordx4 %10, %17, off offset:128 sc0\n\t"
        "global_load_dwordx4 %11, %17, off offset:192 sc0\n\t"
        "global_load_dwordx4 %12, %17, off offset:256 sc0\n\t"
        "global_load_dwordx4 %13, %17, off offset:320 sc0\n\t"
        "global_load_dwordx4 %14, %17, off offset:384 sc0\n\t"
        "global_load_dwordx4 %15, %17, off offset:448 sc0\n\t"
        "s_waitcnt vmcnt(0)"
        : "=&v"(A[0]), "=&v"(A[1]), "=&v"(A[2]), "=&v"(A[3]),
          "=&v"(A[4]), "=&v"(A[5]), "=&v"(A[6]), "=&v"(A[7]),
          "=&v"(C[0]), "=&v"(C[1]), "=&v"(C[2]), "=&v"(C[3]),
          "=&v"(C[4]), "=&v"(C[5]), "=&v"(C[6]), "=&v"(C[7])
        : "v"(ap), "v"(cp)
        : "memory");
    __builtin_amdgcn_sched_barrier(0);

    f32x4 acc0[2], acc1[2];
    acc0[0] = zero4(); acc0[1] = zero4(); acc1[0] = zero4(); acc1[1] = zero4();

    // ---- pure MFMA burst: 48 MFMAs, register A and register B ----
#pragma unroll
    for (int j = 0; j < 8; ++j) {
#pragma unroll
      for (int ct = 0; ct < 2; ++ct) {
        acc0[ct] = MFMA16(A[j], wv0[ct][j], acc0[ct]);
        acc1[ct] = MFMA16(A[j], wv1[ct][j], acc1[ct]);
        acc1[ct] = MFMA16(C[j], wv2[ct][j], acc1[ct]);
      }
    }

    // partials -> LDS
#pragma unroll
    for (int ct = 0; ct < 2; ++ct)
#pragma unroll
      for (int r = 0; r < 4; ++r) {
        const int row = (l >> 4) * 4 + r;
        pbuf[w * 2 + 0][row][ct * 16 + lrow] = acc0[ct][r];
        pbuf[w * 2 + 1][row][ct * 16 + lrow] = acc1[ct][r];
      }
    __syncthreads();

    // reduce over 4 waves + tanh + agent-visible (MALL) store
    if (ep_p == 0) {
      if (cmp_h0) {
        f32x4 sa = zero4();
#pragma unroll
        for (int ww = 0; ww < 4; ++ww)
          sa += *(const f32x4*)&pbuf[ww * 2 + 0][ep_r][ep_c];
        f16x4 o;
#pragma unroll
        for (int i = 0; i < 4; ++i) o[i] = (f16)fast_tanh(sa[i] + (float)pre4[i]);
        st8_ag(h0w + (size_t)(rbase + ep_r) * 1024 + c0 + ep_c, o);
      } else {                          // drain step: carry h0[511] forward
        f16x4 v = ld8_sync(h0p + (size_t)(rbase + ep_r) * 1024 + c0 + ep_c);
        st8_ag(h0w + (size_t)(rbase + ep_r) * 1024 + c0 + ep_c, v);
      }
    } else {
      if (cmp_h1) {
        f32x4 sa = zero4();
#pragma unroll
        for (int ww = 0; ww < 4; ++ww)
          sa += *(const f32x4*)&pbuf[ww * 2 + 1][ep_r][ep_c];
        f16x4 o;
#pragma unroll
        for (int i = 0; i < 4; ++i) o[i] = (f16)fast_tanh(sa[i] + b1v[i]);
        st8_ag(h1w + (size_t)(rbase + ep_r) * 1024 + c0 + ep_c, o);
        if (tops && s_loc >= 1)
          *(f16x4*)(tops + ((size_t)(s_loc - 1) * 128 + rbase + ep_r) * 1024 + c0 + ep_c) = o;
      } else if (h1_copy) {             // dec fill step: carry h1_enc[511]
        f16x4 v = ld8_sync(h1p + (size_t)(rbase + ep_r) * 1024 + c0 + ep_c);
        st8_ag(h1w + (size_t)(rbase + ep_r) * 1024 + c0 + ep_c, v);
      }
    }
    asm volatile("s_waitcnt vmcnt(0)" ::: "memory");   // stores ack'd at MALL
    __syncthreads();                    // whole block done

    if (s_loc == 512) break;            // no in-kernel consumer of last step

    // ---- publish: flag store (system write-through, proven visible) ----
    if (t == 0) {
      const unsigned val = (unsigned)(s_loc + 1);
      asm volatile("global_store_dword %0, %1, off sc0 sc1"
                   :: "v"(flags + fidx), "v"(val) : "memory");
    }
    // prefetch next step's pre0 NOW -> latency hides under next head-poll
    if (ep_p == 0 && s_loc < 511)
      pre_next = *(const f16x4*)(prep_base + (size_t)(s_loc + 1) * 131072);
  }
}

// ---------------------------------------------------------------------------
// log_softmax over rows of 1024: f16 logits in, f32 out.
// ---------------------------------------------------------------------------
__global__ __launch_bounds__(256)
void logsoftmax_rows_h(const f16* __restrict__ in, float* __restrict__ out)
{
  const int row = blockIdx.x;
  const int t = threadIdx.x;
  const f16* p = in + (size_t)row * 1024;
  f16x4 h = *(const f16x4*)(p + t * 4);
  float4 v;
  v.x = (float)h[0]; v.y = (float)h[1]; v.z = (float)h[2]; v.w = (float)h[3];
  float m = fmaxf(fmaxf(v.x, v.y), fmaxf(v.z, v.w));
#pragma unroll
  for (int off = 32; off >= 1; off >>= 1) m = fmaxf(m, __shfl_xor(m, off));
  __shared__ float red[4];
  __shared__ float red2[4];
  const int w = t >> 6;
  if ((t & 63) == 0) red[w] = m;
  __syncthreads();
  m = fmaxf(fmaxf(red[0], red[1]), fmaxf(red[2], red[3]));
  float s = __expf(v.x - m) + __expf(v.y - m) + __expf(v.z - m) + __expf(v.w - m);
#pragma unroll
  for (int off = 32; off >= 1; off >>= 1) s += __shfl_xor(s, off);
  if ((t & 63) == 0) red2[w] = s;
  __syncthreads();
  s = red2[0] + red2[1] + red2[2] + red2[3];
  const float lse = m + __logf(s);
  float4 o;
  o.x = v.x - lse; o.y = v.y - lse; o.z = v.z - lse; o.w = v.w - lse;
  ((float4*)(out + (size_t)row * 1024))[t] = o;
}

// ---------------------------------------------------------------------------
extern "C" void kernel_launch(void* const* d_in, const int* in_sizes, int n_in,
                              void* d_out, int out_size, void* d_ws, size_t ws_size,
                              hipStream_t stream)
{
  (void)in_sizes; (void)n_in; (void)out_size; (void)ws_size;

  const float* X    = (const float*)d_in[0];   // [513][128][1024]
  const float* Y    = (const float*)d_in[1];   // [512][128][1024]
  const float* eWih = (const float*)d_in[2];   // [2][1024][1024]
  const float* eWhh = (const float*)d_in[3];
  const float* ebih = (const float*)d_in[4];   // [2][1024]
  const float* ebhh = (const float*)d_in[5];
  const float* dWih = (const float*)d_in[6];
  const float* dWhh = (const float*)d_in[7];
  const float* dbih = (const float*)d_in[8];
  const float* dbhh = (const float*)d_in[9];
  const float* linW = (const float*)d_in[10];  // [1024][1024]
  const float* linb = (const float*)d_in[11];  // [1024]

  // workspace layout
  char* ws = (char*)d_ws;
  unsigned* flags = (unsigned*)ws;                                // 1KB used
  f16* h0b  = (f16*)(ws + 65536);                                 // 16*256KB = 4MB
  f16* h1b  = (f16*)(ws + 65536 + (16u << 18));                   // 4MB
  f16* wcvt = (f16*)(ws + (9u << 20));                            // 6MB @ 9MB
  f16* pre0 = (f16*)(ws + (16u << 20));                           // 128MB @ 16MB
  f16* tops = (f16*)(ws + (144u << 20));                          // 128MB @ 144MB
  f16* tmpB = tops;                    // 2MB scratch; tops not live until dec rnn
  f16* logits16 = pre0;                // 113MB; pre0 dead after dec rnn

  const size_t LAYER1 = 1024 * 1024;
  const size_t MEG = 1024 * 1024;
  const int M = 512 * 128;

  // zero flags + both h rings
  hipMemsetAsync(d_ws, 0, 65536 + (32u << 18), stream);

  dim3 ggrid(8, 512);
  dim3 cgrid3(1024, 3);

  // encoder input-GEMM B (Wih0_e) -> f16 scratch, then GEMM
  cvt_w1<<<1024, 256, 0, stream>>>(eWih, tmpB);
  gemm_bias<float, true, true><<<ggrid, 256, 0, stream>>>(
      X, X, 1 << 30, tmpB, ebih, ebhh, pre0, M, 1024, 1024);

  // encoder recurrent weights -> f16, then encoder recurrence
  cvt_w3<<<cgrid3, 256, 0, stream>>>(eWhh, eWih + LAYER1, eWhh + LAYER1, wcvt);
  rnn_phase<<<256, 256, 0, stream>>>(
      pre0, h0b, h1b, flags,
      wcvt, wcvt + MEG, wcvt + 2 * MEG, ebih + 1024, ebhh + 1024,
      nullptr, 0);

  // decoder input-GEMM B (Wih0_d) -> f16 scratch (enc GEMM done), then GEMM
  cvt_w1<<<1024, 256, 0, stream>>>(dWih, tmpB);
  gemm_bias<float, true, true><<<ggrid, 256, 0, stream>>>(
      X + (size_t)512 * 128 * 1024, Y, 128, tmpB, dbih, dbhh, pre0, M, 1024, 1024);

  // reset flags for decoder phase (hidden state carries over)
  hipMemsetAsync(d_ws, 0, 4096, stream);

  // decoder recurrent weights -> f16 (after enc rnn: buffer reuse), then rnn
  cvt_w3<<<cgrid3, 256, 0, stream>>>(dWhh, dWih + LAYER1, dWhh + LAYER1, wcvt);
  rnn_phase<<<256, 256, 0, stream>>>(
      pre0, h0b, h1b, flags,
      wcvt, wcvt + MEG, wcvt + 2 * MEG, dbih + 1024, dbhh + 1024,
      tops, 513);

  // final linear: linW -> f16 (wcvt free after dec rnn); f16 logits -> scratch
  cvt_w1<<<1024, 256, 0, stream>>>(linW, wcvt);
  gemm_bias<f16, true, true><<<ggrid, 256, 0, stream>>>(
      tops, tops, 1 << 30, wcvt, linb, nullptr, logits16, M, 1024, 1024);

  // log_softmax: f16 logits -> f32 d_out
  logsoftmax_rows_h<<<M, 256, 0, stream>>>(logits16, (float*)d_out);
}